// Round 12
// baseline (3842.764 us; speedup 1.0000x reference)
//
#include <hip/hip_runtime.h>
#include <math.h>

// ---------------------------------------------------------------------------
// TensorProcessor: conv3d(1,3,1)+bias+relu -> Tucker-HOOI core (8,6,6,6)
// Round 17: retire the LAST exact eigh (keigh_init, ~300us = the N=128
// 2-barrier tridiag floor). Init now uses oversampled cold-start subspace
// iteration (ksub_init: random N x (R+2) start, MGS, 12 power steps,
// Rayleigh-Ritz, keep top R). The exact eig_body/ESm machinery is deleted.
// Evidence: de-exact-ing sweeps moved absmax 12.375->8.31 (all passed);
// init error is absorbed by 5 HOOI sweeps x 3 warm power steps.
// conv / transposed-tile kgram_big / two-stage reduce / contractions /
// per-sweep ksub unchanged from round 16.
// ---------------------------------------------------------------------------

// ws layout (float offsets)
constexpr long long OFF_T   = 0LL;                 // 26,214,400
constexpr long long OFF_TC  = 26214400LL;          // 6,553,600
constexpr long long OFF_TB  = 32768000LL;          // 1,572,864
constexpr long long OFF_PART= OFF_TC;              // <=6,553,600 (init only)
constexpr long long OFF_P2  = OFF_TB;              // <=524,288 (init only)
constexpr long long OFF_TD0a= OFF_TC;              // mode0 (32,6,6,64)=73,728
constexpr long long OFF_TD0b= OFF_TC + 131072;     // mode0 (32,6,6,6)=6,912
constexpr long long OFF_TD  = OFF_TB + 1000000LL;  // sweep small tensors
constexpr long long OFF_G0  = OFF_TB + 1400000LL;  // 1,024
constexpr long long OFF_G1  = OFF_G0 + 1024;       // 10,000
constexpr long long OFF_G2  = OFF_G1 + 10000;      // 16,384
constexpr long long OFF_G3  = OFF_G2 + 16384;      // 4,096
constexpr long long OFF_F0  = 34340864LL;          // 256
constexpr long long OFF_F1  = OFF_F0 + 256;        // 600
constexpr long long OFF_F2  = OFF_F1 + 600;        // 768
constexpr long long OFF_F3  = OFF_F2 + 768;        // 384

__device__ __forceinline__ float rcp_(float x) { return __builtin_amdgcn_rcpf(x); }

template<int CTRL>
__device__ __forceinline__ float dppmovf(float v) {
  return __int_as_float(__builtin_amdgcn_update_dpp(
      0, __float_as_int(v), CTRL, 0xF, 0xF, true));
}
// full 64-lane sum, result in all lanes
__device__ __forceinline__ float wave_sum64(float v) {
  v += dppmovf<0xB1>(v);
  v += dppmovf<0x4E>(v);
  v += dppmovf<0x124>(v);   // row_ror:4
  v += dppmovf<0x128>(v);   // row_ror:8
  v += __shfl_xor(v, 16, 64);
  v += __shfl_xor(v, 32, 64);
  return v;
}

// ---------------- conv + relu ----------------
__global__ void kconv(const float* __restrict__ x, const float* __restrict__ cw,
                      const float* __restrict__ cb, float* __restrict__ t) {
  int idx = blockIdx.x * blockDim.x + threadIdx.x;
  if (idx >= 26214400) return;
  int w  = idx & 63;
  int h  = (idx >> 6) & 127;
  int d  = (idx >> 13) % 100;
  int o  = idx / 819200;
  float acc = cb[o];
#pragma unroll
  for (int i = 0; i < 4; ++i) {
    const float* xi = x + (((long long)i * 100 + d) * 130 + h) * 64 + w;
#pragma unroll
    for (int kh = 0; kh < 3; ++kh)
      acc = fmaf(cw[(o * 4 + i) * 3 + kh], xi[kh * 64], acc);
  }
  t[idx] = fmaxf(acc, 0.f);
}

// ---------------- big gram (init HOSVD): G = X X^T over fibers ----------------
// Transposed tile [cc][DP+4]: fragment reads are float4 (16B-aligned),
// conflict-free; global reads stay coalesced (cc-fast). Grid sized per call.
template<int D, long long QQ, bool TRANS>
__global__ void kgram_big(const float* __restrict__ T, float* __restrict__ part,
                          int P) {
  constexpr int C = 64;
  constexpr int SUB = (D + 63) / 64;
  constexpr int DP = SUB * 64;
  constexpr int STR = DP + 4;                // 16B-aligned float stride
  __shared__ float tile[C * STR];
  const int tid = threadIdx.x;               // 256
  const int ta = tid >> 4, tb = tid & 15;
  float acc[SUB][SUB][4][4];
#pragma unroll
  for (int a = 0; a < SUB; ++a)
#pragma unroll
    for (int b = 0; b < SUB; ++b)
#pragma unroll
      for (int i = 0; i < 4; ++i)
#pragma unroll
        for (int j = 0; j < 4; ++j) acc[a][b][i][j] = 0.f;

  const long long nfib = (long long)P * QQ;
  const int nchunk = (int)(nfib / C);
  for (int ch = blockIdx.x; ch < nchunk; ch += gridDim.x) {
    const long long base = (long long)ch * C;
    __syncthreads();
    if (TRANS) {
      for (int e = tid; e < D * C; e += 256) {
        int a = e & 63, cc = e >> 6;         // a fast -> global coalesced
        tile[cc * STR + a] = T[base * D + e];
      }
    } else {
      for (int e = tid; e < DP * C; e += 256) {
        int cc = e & 63, a = e >> 6;         // cc fast -> global coalesced
        float v = 0.f;
        if (a < D) {
          long long f = base + cc;
          long long p = f / QQ, q = f - p * QQ;   // compile-time QQ
          v = T[(p * D + a) * QQ + q];
        }
        tile[cc * STR + a] = v;
      }
    }
    __syncthreads();
    for (int cc = 0; cc < C; ++cc) {
      const float* tr = &tile[cc * STR];
      float4 av[SUB], bv[SUB];
#pragma unroll
      for (int si = 0; si < SUB; ++si) av[si] = *(const float4*)&tr[si * 64 + ta * 4];
#pragma unroll
      for (int sj = 0; sj < SUB; ++sj) bv[sj] = *(const float4*)&tr[sj * 64 + tb * 4];
#pragma unroll
      for (int si = 0; si < SUB; ++si)
#pragma unroll
        for (int sj = 0; sj < SUB; ++sj) {
          const float a0 = av[si].x, a1 = av[si].y, a2 = av[si].z, a3 = av[si].w;
          const float b0 = bv[sj].x, b1 = bv[sj].y, b2 = bv[sj].z, b3 = bv[sj].w;
          acc[si][sj][0][0] = fmaf(a0, b0, acc[si][sj][0][0]);
          acc[si][sj][0][1] = fmaf(a0, b1, acc[si][sj][0][1]);
          acc[si][sj][0][2] = fmaf(a0, b2, acc[si][sj][0][2]);
          acc[si][sj][0][3] = fmaf(a0, b3, acc[si][sj][0][3]);
          acc[si][sj][1][0] = fmaf(a1, b0, acc[si][sj][1][0]);
          acc[si][sj][1][1] = fmaf(a1, b1, acc[si][sj][1][1]);
          acc[si][sj][1][2] = fmaf(a1, b2, acc[si][sj][1][2]);
          acc[si][sj][1][3] = fmaf(a1, b3, acc[si][sj][1][3]);
          acc[si][sj][2][0] = fmaf(a2, b0, acc[si][sj][2][0]);
          acc[si][sj][2][1] = fmaf(a2, b1, acc[si][sj][2][1]);
          acc[si][sj][2][2] = fmaf(a2, b2, acc[si][sj][2][2]);
          acc[si][sj][2][3] = fmaf(a2, b3, acc[si][sj][2][3]);
          acc[si][sj][3][0] = fmaf(a3, b0, acc[si][sj][3][0]);
          acc[si][sj][3][1] = fmaf(a3, b1, acc[si][sj][3][1]);
          acc[si][sj][3][2] = fmaf(a3, b2, acc[si][sj][3][2]);
          acc[si][sj][3][3] = fmaf(a3, b3, acc[si][sj][3][3]);
        }
    }
  }
  float* pb = part + (long long)blockIdx.x * D * D;
  for (int si = 0; si < SUB; ++si)
    for (int i = 0; i < 4; ++i) {
      int a = si * 64 + ta * 4 + i;
      if (a >= D) continue;
      for (int sj = 0; sj < SUB; ++sj)
        for (int j = 0; j < 4; ++j) {
          int b = sj * 64 + tb * 4 + j;
          if (b >= D) continue;
          pb[a * D + b] = acc[si][sj][i][j];
        }
    }
}

// two-stage reduce: stage1 sums a 1/K slice of b per (k,i); stage2 sums K.
#define RED_K 32
__global__ void kreduce1(const float* __restrict__ part, float* __restrict__ part2,
                         int DD, int nblk) {
  int nb = (DD + 255) >> 8;
  int k = blockIdx.x / nb;
  int i = (blockIdx.x - k * nb) * 256 + threadIdx.x;
  if (i >= DD) return;
  int b0 = (int)((long long)k * nblk / RED_K);
  int b1 = (int)((long long)(k + 1) * nblk / RED_K);
  float s = 0.f;
  for (int b = b0; b < b1; ++b) s += part[(long long)b * DD + i];
  part2[(long long)k * DD + i] = s;
}
__global__ void kreduce2(const float* __restrict__ part2, float* __restrict__ G,
                         int DD) {
  int i = blockIdx.x * 256 + threadIdx.x;
  if (i >= DD) return;
  float s = 0.f;
#pragma unroll 8
  for (int k = 0; k < RED_K; ++k) s += part2[(long long)k * DD + i];
  G[i] = s;
}

// ---------------- small gram (projected Y) ----------------
__global__ void kgram_small(const float* __restrict__ Y, float* __restrict__ G,
                            int P, int d, int Q) {
  int pair = blockIdx.x * blockDim.x + threadIdx.x;
  if (pair >= d * d) return;
  int a = pair / d, b = pair % d;
  float s = 0.f;
  for (int p = 0; p < P; ++p) {
    const float* ya = Y + ((long long)p * d + a) * Q;
    const float* yb = Y + ((long long)p * d + b) * Q;
    for (int q = 0; q < Q; ++q) s = fmaf(ya[q], yb[q], s);
  }
  G[pair] = s;
}

// ---------------- mode contraction: out[p,j,q] = sum_a F[a,j] in[p,a,q] ----------------
template<int R, long long QV>
__global__ void kcontract(const float* __restrict__ in, const float* __restrict__ F,
                          float* __restrict__ out, int P, int d) {
  long long total = (long long)P * QV;
  long long idx = (long long)blockIdx.x * blockDim.x + threadIdx.x;
  if (idx >= total) return;
  long long p = idx / QV, q = idx - p * QV;
  float acc[R];
#pragma unroll
  for (int j = 0; j < R; ++j) acc[j] = 0.f;
  const float* ip = in + (p * d) * QV + q;
  for (int a = 0; a < d; ++a) {
    float v = ip[(long long)a * QV];
#pragma unroll
    for (int j = 0; j < R; ++j) acc[j] = fmaf(F[a * R + j], v, acc[j]);
  }
  float* op = out + (p * R) * QV + q;
#pragma unroll
  for (int j = 0; j < R; ++j) op[(long long)j * QV] = acc[j];
}

// ---------------- subspace iteration core (shared by init and sweeps) ----------------
// Runs STEPS power steps on RP columns held in Q (already orthonormal-ish),
// then Rayleigh-Ritz on the RP x RP projected matrix, keeps top R, canonical
// sign, writes F (N x R). Q/Wm shapes are [RP][132] in LDS.
template<int N, int R, int RP, int TH, int STEPS, int JSW>
__device__ void sub_body(float (*Q)[132], float (*Wm)[132], float* H, float* U,
                         const float* __restrict__ G, float* __restrict__ F) {
  const int tid = threadIdx.x;
  const int lane = tid & 63, wv = tid >> 6;
  constexpr int WAVES = TH / 64;

  for (int step = 0; step < STEPS; ++step) {
    // Wm[j][k] = sum_a G[k][a] * Q[j][a]   (consecutive tids share k -> G row broadcast)
    for (int idx = tid; idx < N * RP; idx += TH) {
      int k = idx / RP, j = idx - k * RP;
      const float* gr = G + (long long)k * N;
      float acc = 0.f;
      for (int a = 0; a < N; ++a) acc = fmaf(gr[a], Q[j][a], acc);
      Wm[j][k] = acc;
    }
    __syncthreads();
    if (step < STEPS - 1) {
      if (wv == 0) {                     // MGS rows of Wm -> Q (single wave)
        const int k1 = lane, k2 = lane + 64;
        for (int j = 0; j < RP; ++j) {
          float vj1 = (k1 < N) ? Wm[j][k1] : 0.f;
          float vj2 = (k2 < N) ? Wm[j][k2] : 0.f;
          for (int i2 = 0; i2 < j; ++i2) {
            float a1 = (k1 < N) ? Q[i2][k1] : 0.f;
            float a2 = (k2 < N) ? Q[i2][k2] : 0.f;
            float p = wave_sum64(vj1 * a1 + vj2 * a2);
            vj1 -= p * a1; vj2 -= p * a2;
          }
          float nn2 = wave_sum64(vj1 * vj1 + vj2 * vj2);
          float inv = rsqrtf(fmaxf(nn2, 1e-33f));
          vj1 *= inv; vj2 *= inv;
          if (k1 < N) Q[j][k1] = vj1;
          if (k2 < N) Q[j][k2] = vj2;
        }
      }
      __syncthreads();
    }
  }
  // H = Q^T (G Q): H[i][j] = sum_k Q[i][k] * Wm[j][k]
  if (tid < RP * RP) {
    int i = tid / RP, j = tid - i * RP;
    float s = 0.f;
    for (int k = 0; k < N; ++k) s = fmaf(Q[i][k], Wm[j][k], s);
    H[i * RP + j] = s;
  }
  __syncthreads();
  // Jacobi eigh of H (RP x RP), sort desc, keep top R: U[j*R+i]
  if (tid == 0) {
    float A[RP][RP], V[RP][RP];
    for (int i = 0; i < RP; ++i)
      for (int j = 0; j < RP; ++j) { A[i][j] = H[i * RP + j]; V[i][j] = (i == j) ? 1.f : 0.f; }
    for (int sw = 0; sw < JSW; ++sw)
      for (int p = 0; p < RP - 1; ++p)
        for (int qj = p + 1; qj < RP; ++qj) {
          float apq = A[p][qj];
          if (fabsf(apq) < 1e-12f) continue;
          float theta = 0.5f * (A[qj][qj] - A[p][p]) / apq;
          float t = ((theta >= 0.f) ? 1.f : -1.f) / (fabsf(theta) + sqrtf(theta * theta + 1.f));
          float c = rsqrtf(t * t + 1.f);
          float s = t * c;
          for (int k2 = 0; k2 < RP; ++k2) {
            float akp = A[k2][p], akq = A[k2][qj];
            A[k2][p] = c * akp - s * akq;
            A[k2][qj] = s * akp + c * akq;
          }
          for (int k2 = 0; k2 < RP; ++k2) {
            float apk = A[p][k2], aqk = A[qj][k2];
            A[p][k2] = c * apk - s * aqk;
            A[qj][k2] = s * apk + c * aqk;
          }
          for (int k2 = 0; k2 < RP; ++k2) {
            float vkp = V[k2][p], vkq = V[k2][qj];
            V[k2][p] = c * vkp - s * vkq;
            V[k2][qj] = s * vkp + c * vkq;
          }
        }
    int ord[RP];
    for (int i = 0; i < RP; ++i) ord[i] = i;
    for (int i = 0; i < RP; ++i) {
      int mi = i;
      for (int j = i + 1; j < RP; ++j)
        if (A[ord[j]][ord[j]] > A[ord[mi]][ord[mi]]) mi = j;
      int t2 = ord[i]; ord[i] = ord[mi]; ord[mi] = t2;
    }
    for (int i = 0; i < R; ++i)
      for (int j = 0; j < RP; ++j) U[j * R + i] = V[j][ord[i]];
  }
  __syncthreads();
  // Wm[i][k] = sum_j U[j][i] * Q[j][k]   (rotate into Ritz vectors, top R)
  for (int idx = tid; idx < N * R; idx += TH) {
    int k = idx / R, i = idx - k * R;
    float s = 0.f;
#pragma unroll
    for (int j = 0; j < RP; ++j) s = fmaf(U[j * R + i], Q[j][k], s);
    Wm[i][k] = s;
  }
  __syncthreads();
  // canonical sign + write F
  for (int vec = wv; vec < R; vec += WAVES) {
    float* v = &Wm[vec][0];
    float ma = -1.f; int mi = 0x7fffffff;
    for (int k = lane; k < N; k += 64) {
      float a = fabsf(v[k]);
      if (a > ma || (a == ma && k < mi)) { ma = a; mi = k; }
    }
#pragma unroll
    for (int off = 32; off > 0; off >>= 1) {
      float oa = __shfl_down(ma, off, 64);
      int oi = __shfl_down(mi, off, 64);
      if (oa > ma || (oa == ma && oi < mi)) { ma = oa; mi = oi; }
    }
    mi = __shfl(mi, 0, 64);
    float sg = (v[mi] < 0.f) ? -1.f : 1.f;
    for (int k = lane; k < N; k += 64) F[k * R + vec] = sg * v[k];
  }
}

// ---------------- warm-started subspace refinement (sweeps) ----------------
template<int N, int R, int TH, int STEPS>
__global__ __launch_bounds__(TH, 1)
void ksub(const float* __restrict__ G, float* __restrict__ F) {
  __shared__ float Q[R][132];
  __shared__ float Wm[R][132];
  __shared__ float H[R * R];
  __shared__ float U[R * R];
  const int tid = threadIdx.x;
  for (int idx = tid; idx < N * R; idx += TH) {
    int k = idx / R, j = idx - k * R;
    Q[j][k] = F[idx];
  }
  __syncthreads();
  sub_body<N, R, R, TH, STEPS, 8>(Q, Wm, H, U, G, F);
}

// ---------------- cold-start oversampled subspace init ----------------
template<int N, int R, int TH>
__device__ void sub_init_body(const float* __restrict__ G, float* __restrict__ F) {
  constexpr int RP = R + 2;
  __shared__ float Q[RP][132];
  __shared__ float Wm[RP][132];
  __shared__ float H[RP * RP];
  __shared__ float U[RP * R];
  const int tid = threadIdx.x;
  const int lane = tid & 63, wv = tid >> 6;
  // deterministic pseudo-random start
  for (int idx = tid; idx < N * RP; idx += TH) {
    int k = idx / RP, j = idx - k * RP;
    unsigned h = (unsigned)(k * 1103515245 + j * 747796405 + 2891336453u);
    h ^= h >> 16; h *= 2246822519u; h ^= h >> 13;
    Q[j][k] = ((float)(h & 0xFFFF) * (1.f / 32768.f)) - 1.f;
  }
  __syncthreads();
  // initial MGS (single wave)
  if (wv == 0) {
    const int k1 = lane, k2 = lane + 64;
    for (int j = 0; j < RP; ++j) {
      float vj1 = (k1 < N) ? Q[j][k1] : 0.f;
      float vj2 = (k2 < N) ? Q[j][k2] : 0.f;
      for (int i2 = 0; i2 < j; ++i2) {
        float a1 = (k1 < N) ? Q[i2][k1] : 0.f;
        float a2 = (k2 < N) ? Q[i2][k2] : 0.f;
        float p = wave_sum64(vj1 * a1 + vj2 * a2);
        vj1 -= p * a1; vj2 -= p * a2;
      }
      float nn2 = wave_sum64(vj1 * vj1 + vj2 * vj2);
      float inv = rsqrtf(fmaxf(nn2, 1e-33f));
      vj1 *= inv; vj2 *= inv;
      if (k1 < N) Q[j][k1] = vj1;
      if (k2 < N) Q[j][k2] = vj2;
    }
  }
  __syncthreads();
  sub_body<N, R, RP, TH, 12, 7>(Q, Wm, H, U, G, F);
}

__global__ __launch_bounds__(1024, 1)
void ksub_init4(const float* G0, float* F0, const float* G1, float* F1,
                const float* G2, float* F2, const float* G3, float* F3) {
  if (blockIdx.x == 0)      sub_init_body<32, 8, 1024>(G0, F0);
  else if (blockIdx.x == 1) sub_init_body<100, 6, 1024>(G1, F1);
  else if (blockIdx.x == 2) sub_init_body<128, 6, 1024>(G2, F2);
  else                      sub_init_body<64, 6, 1024>(G3, F3);
}

// ---------------------------------------------------------------------------
extern "C" void kernel_launch(void* const* d_in, const int* in_sizes, int n_in,
                              void* d_out, int out_size, void* d_ws, size_t ws_size,
                              hipStream_t stream) {
  (void)in_sizes; (void)n_in; (void)out_size; (void)ws_size;
  const float* x  = (const float*)d_in[0];
  const float* cw = (const float*)d_in[1];
  const float* cb = (const float*)d_in[2];
  float* out = (float*)d_out;
  float* ws  = (float*)d_ws;

  float* T    = ws + OFF_T;
  float* TC   = ws + OFF_TC;
  float* TB   = ws + OFF_TB;
  float* PART = ws + OFF_PART;
  float* P2   = ws + OFF_P2;
  float* TD0a = ws + OFF_TD0a;
  float* TD0b = ws + OFF_TD0b;
  float* TD   = ws + OFF_TD;
  float* G0   = ws + OFF_G0;
  float* G1   = ws + OFF_G1;
  float* G2   = ws + OFF_G2;
  float* G3   = ws + OFF_G3;
  float* F0   = ws + OFF_F0;
  float* F1   = ws + OFF_F1;
  float* F2   = ws + OFF_F2;
  float* F3   = ws + OFF_F3;

  kconv<<<(26214400 + 255) / 256, 256, 0, stream>>>(x, cw, cb, T);

  // ---- HOSVD init: 4 grams (full-chip grids) + two-stage reduces ----
  kgram_big<32, 819200, false><<<1024, 256, 0, stream>>>(T, PART, 1);
  kreduce1<<<RED_K * 4, 256, 0, stream>>>(PART, P2, 1024, 1024);
  kreduce2<<<4, 256, 0, stream>>>(P2, G0, 1024);
  kgram_big<100, 8192, false><<<640, 256, 0, stream>>>(T, PART, 32);
  kreduce1<<<RED_K * 40, 256, 0, stream>>>(PART, P2, 10000, 640);
  kreduce2<<<40, 256, 0, stream>>>(P2, G1, 10000);
  kgram_big<128, 64, false><<<400, 256, 0, stream>>>(T, PART, 3200);
  kreduce1<<<RED_K * 64, 256, 0, stream>>>(PART, P2, 16384, 400);
  kreduce2<<<64, 256, 0, stream>>>(P2, G2, 16384);
  kgram_big<64, 1, true><<<1536, 256, 0, stream>>>(T, PART, 409600);
  kreduce1<<<RED_K * 16, 256, 0, stream>>>(PART, P2, 4096, 1536);
  kreduce2<<<16, 256, 0, stream>>>(P2, G3, 4096);

  ksub_init4<<<4, 1024, 0, stream>>>(G0, F0, G1, F1, G2, F2, G3, F3);

  // ---- HOOI sweeps: warm-started subspace refinement everywhere;
  //      sweep 4 gets an extra power step (STEPS=4) as the accuracy anchor ----
  for (int sweep = 0; sweep < 5; ++sweep) {
    const bool last = (sweep == 4);
    // mode 0
    kcontract<6, 8192><<<1024, 256, 0, stream>>>(T, F1, TB, 32, 100);
    kcontract<6, 64><<<48, 256, 0, stream>>>(TB, F2, TD0a, 192, 128);
    kcontract<6, 1><<<5, 256, 0, stream>>>(TD0a, F3, TD0b, 1152, 64);
    kgram_small<<<4, 256, 0, stream>>>(TD0b, G0, 1, 32, 216);
    if (last) ksub<32, 8, 256, 4><<<1, 256, 0, stream>>>(G0, F0);
    else      ksub<32, 8, 256, 3><<<1, 256, 0, stream>>>(G0, F0);
    // TC = T x0 F0 (reused by modes 1,2,3 and the final core)
    kcontract<8, 819200><<<3200, 256, 0, stream>>>(T, F0, TC, 1, 32);
    // mode 1
    kcontract<6, 64><<<200, 256, 0, stream>>>(TC, F2, TB, 800, 128);
    kcontract<6, 1><<<19, 256, 0, stream>>>(TB, F3, TD, 4800, 64);
    kgram_small<<<40, 256, 0, stream>>>(TD, G0, 8, 100, 36);
    if (last) ksub<100, 6, 1024, 4><<<1, 1024, 0, stream>>>(G0, F1);
    else      ksub<100, 6, 1024, 3><<<1, 1024, 0, stream>>>(G0, F1);
    // mode 2 (TB = TC x1 F1 also reused by mode 3)
    kcontract<6, 8192><<<256, 256, 0, stream>>>(TC, F1, TB, 8, 100);
    kcontract<6, 1><<<24, 256, 0, stream>>>(TB, F3, TD, 6144, 64);
    kgram_small<<<64, 256, 0, stream>>>(TD, G0, 48, 128, 6);
    if (last) ksub<128, 6, 1024, 4><<<1, 1024, 0, stream>>>(G0, F2);
    else      ksub<128, 6, 1024, 3><<<1, 1024, 0, stream>>>(G0, F2);
    // mode 3 (reuses TB from mode 2)
    kcontract<6, 64><<<12, 256, 0, stream>>>(TB, F2, TD, 48, 128);
    kgram_small<<<16, 256, 0, stream>>>(TD, G0, 288, 64, 1);
    if (last) ksub<64, 6, 512, 4><<<1, 512, 0, stream>>>(G0, F3);
    else      ksub<64, 6, 512, 3><<<1, 512, 0, stream>>>(G0, F3);
  }

  // ---- core = (TC) x1 F1 x2 F2 x3 F3 -> (8,6,6,6) ----
  kcontract<6, 8192><<<256, 256, 0, stream>>>(TC, F1, TB, 8, 100);
  kcontract<6, 64><<<12, 256, 0, stream>>>(TB, F2, TD, 48, 128);
  kcontract<6, 1><<<2, 256, 0, stream>>>(TD, F3, out, 288, 64);
}